// Round 16
// baseline (32.069 us; speedup 1.0000x reference)
//
#include <hip/hip_runtime.h>
#include <math.h>

#define EMBED 512
#define HEADS 8
#define HDIM 64
#define SLEN 2048
#define BATCH 2
#define HALFW 128
#define NCHUNK 32
#define INV_SCALE 0.044194173824159216f  // 1/sqrt(512)

typedef short bf16x8 __attribute__((ext_vector_type(8)));
typedef short s16x4  __attribute__((ext_vector_type(4)));
typedef float f32x4  __attribute__((ext_vector_type(4)));

#define MFMA16(a, b, c) __builtin_amdgcn_mfma_f32_16x16x32_bf16(a, b, c, 0, 0, 0)

__device__ __forceinline__ short f2bf(float x) {
    union { float f; unsigned u; } v; v.f = x;
    unsigned r = v.u + 0x7FFFu + ((v.u >> 16) & 1u);  // RNE
    return (short)(r >> 16);
}

// Blocked-frag layout for a 64x64 bf16 tile (global AND LDS), XOR-swizzled:
// 16B fragment (row, seg) at short index ((seg*64) + (row^seg)) * 8.
__device__ __forceinline__ int lidx(int row, int seg) {
    return (((seg << 6) + (row ^ seg)) << 3);
}

// async global->LDS, 16B per lane. dest: wave-uniform base, HW adds lane*16.
__device__ __forceinline__ void gll16(const short* g, short* l) {
    __builtin_amdgcn_global_load_lds(
        (const __attribute__((address_space(1))) unsigned int*)g,
        (__attribute__((address_space(3))) unsigned int*)l, 16, 0, 0);
}

// 256-thread version: 2 gll16 per 8KB tile
__device__ __forceinline__ void stage_tile(const short* s, short* d, int t) {
    int off = t * 8;
    int wb  = (t >> 6) * 512;
    gll16(s + off,        d + wb);
    gll16(s + 2048 + off, d + 2048 + wb);
}

// 512-thread version: ONE gll16 covers a full 8KB chunk (identity layout)
__device__ __forceinline__ void stage_chunk512(const short* s0, const short* s1,
                                               short* d0, short* d1, int t) {
    int off = t * 8;              // shorts: 512 lanes x 16B = 8KB
    int wb  = (t >> 6) * 512;     // wave-uniform LDS base (shorts)
    gll16(s0 + off, d0 + wb);
    gll16(s1 + off, d1 + wb);
}

// ---------------------------------------------------------------------------
// Kernel 1: prepass v2 (unchanged from R14/R15), half-chunk granularity.
// ---------------------------------------------------------------------------
__global__ __launch_bounds__(256) void prepass(
    const float* __restrict__ q, const float* __restrict__ k,
    const float* __restrict__ v, const int* __restrict__ mask,
    const float* __restrict__ fcw,
    short* __restrict__ Kbf, short* __restrict__ Vbf, short* __restrict__ Wbf,
    float* __restrict__ gnum_part, float* __restrict__ gden_part,
    float* __restrict__ vsum_part, float* __restrict__ nval_part) {
    int d = blockIdx.x;
    int x = d & 7, i = d >> 3;            // 136 works per XCD
    int hb8 = x * 2 + (i >= 68);          // 0..15 (= b*8 + h)
    int ii  = (i >= 68) ? (i - 68) : i;   // 0..67
    int h = hb8 & 7, b = hb8 >> 3;
    int t = threadIdx.x, w = t >> 6, l = t & 63;

    if (ii >= 64) {               // ---- fc_w tile -> Wbf frags ----
        int widx = hb8 * 4 + (ii - 64);   // 0..63
        int nb = widx >> 3, kt = widx & 7;
        size_t base = (size_t)(nb * 8 + kt) * 4096;
        int row = t >> 3, sg = t & 7;
        #pragma unroll
        for (int p = 0; p < 2; ++p) {
            int r2 = row + p * 32;
            const float* src = fcw + (size_t)(nb * 64 + r2) * EMBED + kt * 64 + sg * 8;
            float4 f0 = *(const float4*)(src);
            float4 f1 = *(const float4*)(src + 4);
            bf16x8 o;
            o[0] = f2bf(f0.x); o[1] = f2bf(f0.y); o[2] = f2bf(f0.z); o[3] = f2bf(f0.w);
            o[4] = f2bf(f1.x); o[5] = f2bf(f1.y); o[6] = f2bf(f1.z); o[7] = f2bf(f1.w);
            *(bf16x8*)&Wbf[base + lidx(r2, sg)] = o;
        }
        return;
    }

    int ch  = ii;                 // half-chunk 0..63
    int c   = ch >> 1;            // 64-key chunk
    int rof = (ch & 1) * 32;      // row offset within chunk tile
    int j0  = ch * 32;            // global key start

    __shared__ float q0s[HDIM];
    __shared__ float wls[32];
    __shared__ int   m_s[32];
    __shared__ float vbuf[32][68];
    __shared__ float red[4][HDIM];
    __shared__ float redv[4][HDIM];

    int row = t >> 3, sg = t & 7;

    // A: K/V loads first (oldest in FIFO)
    const float* ksrc = k + ((size_t)b * SLEN + j0 + row) * EMBED + h * HDIM + sg * 8;
    const float* vsrc = v + ((size_t)b * SLEN + j0 + row) * EMBED + h * HDIM + sg * 8;
    float4 kf0 = *(const float4*)(ksrc);
    float4 kf1 = *(const float4*)(ksrc + 4);
    float4 vf0 = *(const float4*)(vsrc);
    float4 vf1 = *(const float4*)(vsrc + 4);

    // B: q/mask -> LDS (overlaps K/V HBM latency)
    if (t < 64) q0s[t] = q[(size_t)b * SLEN * EMBED + h * HDIM + t];
    else if (t < 96) m_s[t - 64] = mask[b * SLEN + j0 + (t - 64)];
    __syncthreads();

    size_t fragbase = ((size_t)(b * HEADS + h) * NCHUNK + c) * 4096;

    *(float4*)&vbuf[row][sg * 8]     = vf0;
    *(float4*)&vbuf[row][sg * 8 + 4] = vf1;

    {
        float dot = q0s[sg*8+0]*kf0.x + q0s[sg*8+1]*kf0.y + q0s[sg*8+2]*kf0.z + q0s[sg*8+3]*kf0.w
                  + q0s[sg*8+4]*kf1.x + q0s[sg*8+5]*kf1.y + q0s[sg*8+6]*kf1.z + q0s[sg*8+7]*kf1.w;
        dot += __shfl_xor(dot, 1, 64);
        dot += __shfl_xor(dot, 2, 64);
        dot += __shfl_xor(dot, 4, 64);
        if (sg == 0) wls[row] = __expf(dot * INV_SCALE);
        if (!m_s[row]) {
            kf0 = make_float4(0.f, 0.f, 0.f, 0.f);
            kf1 = make_float4(0.f, 0.f, 0.f, 0.f);
        }
        bf16x8 o;
        o[0] = f2bf(kf0.x); o[1] = f2bf(kf0.y); o[2] = f2bf(kf0.z); o[3] = f2bf(kf0.w);
        o[4] = f2bf(kf1.x); o[5] = f2bf(kf1.y); o[6] = f2bf(kf1.z); o[7] = f2bf(kf1.w);
        *(bf16x8*)&Kbf[fragbase + lidx(rof + row, sg)] = o;
    }
    __syncthreads();

    float num = 0.f, vs = 0.f;
    #pragma unroll
    for (int jj = 0; jj < 8; ++jj) {
        int jl = w * 8 + jj;
        float vv = vbuf[jl][l];
        num += wls[jl] * vv;
        if (m_s[jl]) vs += vv;
    }
    red[w][l] = num;
    redv[w][l] = vs;

    {
        int jseg = (ch & 1) * 4 + w;
        bf16x8 o;
        #pragma unroll
        for (int e = 0; e < 8; ++e) o[e] = f2bf(vbuf[w * 8 + e][l]);
        *(bf16x8*)&Vbf[fragbase + lidx(l, jseg)] = o;
    }
    __syncthreads();

    if (w == 0) {
        gnum_part[((size_t)(b * HEADS + h) * 64 + ch) * HDIM + l] =
            red[0][l] + red[1][l] + red[2][l] + red[3][l];
        vsum_part[((size_t)b * 64 + ch) * EMBED + h * HDIM + l] =
            redv[0][l] + redv[1][l] + redv[2][l] + redv[3][l];
    } else if (w == 1) {
        float s = (l < 32) ? wls[l] : 0.f;
        #pragma unroll
        for (int off = 32; off > 0; off >>= 1) s += __shfl_xor(s, off, 64);
        if (l == 0) gden_part[(size_t)(b * HEADS + h) * 64 + ch] = s;
    } else if (w == 2 && h == 0) {
        float cc = (l < 32 && m_s[l]) ? 1.f : 0.f;
        #pragma unroll
        for (int off = 32; off > 0; off >>= 1) cc += __shfl_xor(cc, off, 64);
        if (l == 0) nval_part[b * 64 + ch] = cc;
    }
}

// ---------------------------------------------------------------------------
// Kernel 2: windowed attention v12 — 128-row tiles, 512 thr (8 waves),
// grid 256 (1 block/CU, no tail). ~7 chunks per 128 rows (vs 10 before),
// 30% less staging; chunk window now CONTAINS key r0-129 (no fixup path).
// 4-buffer K/V, 3-ahead counted vmcnt (2 loads/chunk -> waits 4/2/0).
// ---------------------------------------------------------------------------
__global__ __launch_bounds__(512) void windowed_attn_v12(
    const float* __restrict__ q,
    const short* __restrict__ Kbf, const short* __restrict__ Vbf,
    const float* __restrict__ gnum_part, const float* __restrict__ gden_part,
    const float* __restrict__ vsum_part, const float* __restrict__ nval_part,
    short* __restrict__ Abf) {
    int dsp = blockIdx.x;                    // 0..255
    int x = dsp & 7, i = dsp >> 3;           // XCD x, 32 works per XCD
    int hb8 = x * 2 + (i >= 16);             // matches prepass placement
    int tlw = i & 15;                        // 128-row tile 0..15
    int h = hb8 & 7, b = hb8 >> 3;
    int r0 = tlw * 128;
    int t = threadIdx.x, w = t >> 6, l = t & 63;   // w 0..7
    int lg = l >> 4, lr = l & 15;

    __shared__ __align__(16) short kv_s[2][4][4096];   // [0]=K, [1]=V (64 KB)
    __shared__ __align__(16) short wT_s[8][16][72];
    __shared__ float rsum[128];
    __shared__ float vred[8][64];
    __shared__ float gred[8][64];
    __shared__ float nv_s, gd_s;

    size_t hb = (size_t)(b * HEADS + h) * NCHUNK;
    int bh = b * HEADS + h;

    int c0 = (r0 - 129) >> 6; if (c0 < 0) c0 = 0;
    int c1 = (r0 + 254) >> 6; if (c1 > NCHUNK - 1) c1 = NCHUNK - 1;
    // tiles 0/15: 4-5 chunks; interior: 7. Always >= 4 -> 3-deep prologue ok.

    // ---- A: scalar prologue loads first (oldest in FIFO) ----
    const float* qrow = q + ((size_t)b * SLEN + r0 + w * 16 + lr) * EMBED + h * HDIM;
    float4 a0 = *(const float4*)(qrow + lg * 8);
    float4 a1 = *(const float4*)(qrow + lg * 8 + 4);
    float4 a2 = *(const float4*)(qrow + 32 + lg * 8);
    float4 a3 = *(const float4*)(qrow + 32 + lg * 8 + 4);
    float vtmp[8];
    #pragma unroll
    for (int cc = 0; cc < 8; ++cc)
        vtmp[cc] = vsum_part[((size_t)b * 64 + w * 8 + cc) * EMBED + h * HDIM + l];
    float nvt = (w == 0) ? nval_part[b * 64 + l] : 0.f;
    float gtmp[8];
    float gdt = 0.f;
    if (tlw == 0) {
        #pragma unroll
        for (int cc = 0; cc < 8; ++cc)
            gtmp[cc] = gnum_part[((size_t)bh * 64 + w * 8 + cc) * HDIM + l];
        if (w == 1) gdt = gden_part[(size_t)bh * 64 + l];
    }
    __builtin_amdgcn_sched_barrier(0);

    // ---- B: 3 chunk stages back-to-back (2 gll16 each) ----
    stage_chunk512(Kbf + (hb + c0) * 4096, Vbf + (hb + c0) * 4096,
                   &kv_s[0][0][0], &kv_s[1][0][0], t);
    stage_chunk512(Kbf + (hb + c0 + 1) * 4096, Vbf + (hb + c0 + 1) * 4096,
                   &kv_s[0][1][0], &kv_s[1][1][0], t);
    stage_chunk512(Kbf + (hb + c0 + 2) * 4096, Vbf + (hb + c0 + 2) * 4096,
                   &kv_s[0][2][0], &kv_s[1][2][0], t);
    __builtin_amdgcn_sched_barrier(0);

    // ---- C: consume scalars (waits retire only oldest loads) ----
    bf16x8 qb0, qb1;
    qb0[0] = f2bf(a0.x); qb0[1] = f2bf(a0.y); qb0[2] = f2bf(a0.z); qb0[3] = f2bf(a0.w);
    qb0[4] = f2bf(a1.x); qb0[5] = f2bf(a1.y); qb0[6] = f2bf(a1.z); qb0[7] = f2bf(a1.w);
    qb1[0] = f2bf(a2.x); qb1[1] = f2bf(a2.y); qb1[2] = f2bf(a2.z); qb1[3] = f2bf(a2.w);
    qb1[4] = f2bf(a3.x); qb1[5] = f2bf(a3.y); qb1[6] = f2bf(a3.z); qb1[7] = f2bf(a3.w);
    {
        float vp = 0.f;
        #pragma unroll
        for (int cc = 0; cc < 8; ++cc) vp += vtmp[cc];
        vred[w][l] = vp;
        if (w == 0) {
            float nvv = nvt;
            #pragma unroll
            for (int off = 32; off > 0; off >>= 1) nvv += __shfl_xor(nvv, off, 64);
            if (l == 0) nv_s = nvv;
        }
        if (tlw == 0) {
            float gp = 0.f;
            #pragma unroll
            for (int cc = 0; cc < 8; ++cc) gp += gtmp[cc];
            gred[w][l] = gp;
            if (w == 1) {
                float gdd = gdt;
                #pragma unroll
                for (int off = 32; off > 0; off >>= 1) gdd += __shfl_xor(gdd, off, 64);
                if (l == 0) gd_s = gdd;
            }
        }
    }

    int center = r0 + w * 16 + lr - 1;       // this lane's output-row center
    int lo = center - HALFW, hi = center + HALFW;

    f32x4 pv[4];
    #pragma unroll
    for (int dt = 0; dt < 4; ++dt) pv[dt] = (f32x4){0.f, 0.f, 0.f, 0.f};
    float dacc = 0.f;

    int bi = 0;
    for (int c = c0; c <= c1; ++c) {
        // wait for stage(c); keep up to 2 newer chunk-stages (4 loads) in flight
        int rem = c1 - c;
        if (rem >= 2)      { asm volatile("s_waitcnt vmcnt(4)" ::: "memory"); }
        else if (rem == 1) { asm volatile("s_waitcnt vmcnt(2)" ::: "memory"); }
        else               { asm volatile("s_waitcnt vmcnt(0)" ::: "memory"); }
        __syncthreads();

        int jc = c * 64;
        // ---- QK^T (S^T): A = K rows, B = Q ----
        #pragma unroll
        for (int jt = 0; jt < 4; ++jt) {
            bf16x8 ka0 = *(const bf16x8*)&kv_s[0][bi][lidx(jt * 16 + lr, lg)];
            bf16x8 ka1 = *(const bf16x8*)&kv_s[0][bi][lidx(jt * 16 + lr, 4 + lg)];
            f32x4 sT = (f32x4){0.f, 0.f, 0.f, 0.f};
            sT = MFMA16(ka0, qb0, sT);
            sT = MFMA16(ka1, qb1, sT);
            int jbase = jc + jt * 16 + lg * 4;
            s16x4 wq;
            #pragma unroll
            for (int r = 0; r < 4; ++r) {
                int j = jbase + r;
                float wgt = (j >= lo && j <= hi) ? (__expf(sT[r] * INV_SCALE) - 1.f) : 0.f;
                dacc += wgt;
                wq[r] = f2bf(wgt);
            }
            *(s16x4*)&wT_s[w][lr][jt * 16 + lg * 4] = wq;
        }

        // ---- PV: A = w^T strip (wave-private), B = V^T frags ----
        bf16x8 wa0 = *(const bf16x8*)&wT_s[w][lr][lg * 8];
        bf16x8 wa1 = *(const bf16x8*)&wT_s[w][lr][32 + lg * 8];
        #pragma unroll
        for (int dt = 0; dt < 4; ++dt) {
            bf16x8 va0 = *(const bf16x8*)&kv_s[1][bi][lidx(dt * 16 + lr, lg)];
            bf16x8 va1 = *(const bf16x8*)&kv_s[1][bi][lidx(dt * 16 + lr, 4 + lg)];
            pv[dt] = MFMA16(wa0, va0, pv[dt]);
            pv[dt] = MFMA16(wa1, va1, pv[dt]);
        }

        // stage chunk c+3 into buffer (bi+3)&3 = buffer of compute(c-1);
        // safe: all waves passed this iter's barrier after finishing c-1.
        if (c + 3 <= c1) {
            int bn = (bi + 3) & 3;
            stage_chunk512(Kbf + (hb + c + 3) * 4096, Vbf + (hb + c + 3) * 4096,
                           &kv_s[0][bn][0], &kv_s[1][bn][0], t);
        }
        bi = (bi + 1) & 3;
    }

    // ---- row-sum reduce (no fixup needed: chunk window covers r0-129) ----
    dacc += __shfl_xor(dacc, 16, 64);
    dacc += __shfl_xor(dacc, 32, 64);
    if (lg == 0) rsum[w * 16 + lr] = dacc;
    __syncthreads();   // also: all waves done with kv_s -> obuf overlay safe

    float nv = nv_s;
    float invden[4];
    #pragma unroll
    for (int r = 0; r < 4; ++r)
        invden[r] = 1.f / (nv + rsum[w * 16 + lg * 4 + r]);

    // ---- epilogue: acc -> LDS fp32 [128][68] (overlays kv_s, 34.8 KB), then
    // gathered 16B frag stores (2 per thread).
    float* obuf = (float*)&kv_s[0][0][0];
    #pragma unroll
    for (int dt = 0; dt < 4; ++dt) {
        int dd = dt * 16 + lr;
        float vs = 0.f;
        #pragma unroll
        for (int ww = 0; ww < 8; ++ww) vs += vred[ww][dd];
        #pragma unroll
        for (int r = 0; r < 4; ++r) {
            int row_local = w * 16 + lg * 4 + r;
            float o;
            if (tlw == 0 && row_local == 0)
                o = (gred[0][dd] + gred[1][dd] + gred[2][dd] + gred[3][dd] +
                     gred[4][dd] + gred[5][dd] + gred[6][dd] + gred[7][dd]) / gd_s;
            else
                o = (pv[dt][r] + vs) * invden[r];
            obuf[row_local * 68 + dd] = o;
        }
    }
    __syncthreads();

    {
        int row = t >> 3, sg = t & 7;        // row 0..63
        #pragma unroll
        for (int p = 0; p < 2; ++p) {
            int r2 = row + p * 64;           // 0..127
            short* Atile = Abf + ((size_t)(b * NCHUNK + tlw * 2 + (r2 >> 6)) * 8 + h) * 4096;
            const float* src = &obuf[r2 * 68 + sg * 8];
            bf16x8 o8;
            #pragma unroll
            for (int e = 0; e < 8; ++e) o8[e] = f2bf(src[e]);
            *(bf16x8*)&Atile[lidx(r2 & 63, sg)] = o8;
        }
    }
}

// ---------------------------------------------------------------------------
// Kernel 3: FC GEMM v6 (unchanged from R15) — A-strip staged once, counted
// vmcnt, LDS-transposed coalesced epilogue.
// ---------------------------------------------------------------------------
__global__ __launch_bounds__(256) void fc_gemm_v6(
    const short* __restrict__ Abf, const short* __restrict__ Wbf,
    const float* __restrict__ bias, float* __restrict__ C) {
    int bm = blockIdx.x;          // 0..63
    int nb = blockIdx.y;          // 0..7
    int t = threadIdx.x, w = t >> 6, l = t & 63;
    int lg = l >> 4, lr = l & 15;
    int wr = w >> 1, wc = w & 1;

    __shared__ __align__(16) short a_s[8][4096];   // full A strip (64 KB)
    __shared__ __align__(16) short w_s[2][4096];   // W dbuf (16 KB)

    stage_tile(Abf + (size_t)(bm * 8 + 0) * 4096, &a_s[0][0], t);
    stage_tile(Wbf + (size_t)(nb * 8 + 0) * 4096, &w_s[0][0], t);
    stage_tile(Wbf + (size_t)(nb * 8 + 1) * 4096, &w_s[1][0], t);
    #pragma unroll
    for (int kt = 1; kt < 8; ++kt)
        stage_tile(Abf + (size_t)(bm * 8 + kt) * 4096, &a_s[kt][0], t);

    f32x4 acc[2][2];
    #pragma unroll
    for (int mt = 0; mt < 2; ++mt)
        #pragma unroll
        for (int nt = 0; nt < 2; ++nt) acc[mt][nt] = (f32x4){0.f, 0.f, 0.f, 0.f};

    for (int kt = 0; kt < 8; ++kt) {
        if (kt == 0)      { asm volatile("s_waitcnt vmcnt(16)" ::: "memory"); }
        else if (kt == 1) { asm volatile("s_waitcnt vmcnt(14)" ::: "memory"); }
        else if (kt < 7)  { asm volatile("s_waitcnt vmcnt(2)"  ::: "memory"); }
        else              { asm volatile("s_waitcnt vmcnt(0)"  ::: "memory"); }
        __syncthreads();

        bf16x8 af[2][2], bf_[2][2];
        #pragma unroll
        for (int mt = 0; mt < 2; ++mt) {
            af[mt][0] = *(const bf16x8*)&a_s[kt][lidx(wr * 32 + mt * 16 + lr, lg)];
            af[mt][1] = *(const bf16x8*)&a_s[kt][lidx(wr * 32 + mt * 16 + lr, 4 + lg)];
        }
        int wbuf = kt & 1;
        #pragma unroll
        for (int nt = 0; nt < 2; ++nt) {
            bf_[nt][0] = *(const bf16x8*)&w_s[wbuf][lidx(wc * 32 + nt * 16 + lr, lg)];
            bf_[nt][1] = *(const bf16x8*)&w_s[wbuf][lidx(wc * 32 + nt * 16 + lr, 4 + lg)];
        }
        #pragma unroll
        for (int mt = 0; mt < 2; ++mt)
            #pragma unroll
            for (int nt = 0; nt < 2; ++nt) {
                acc[mt][nt] = MFMA16(af[mt][0], bf_[nt][0], acc[mt][nt]);
                acc[mt][nt] = MFMA16(af[mt][1], bf_[nt][1], acc[mt][nt]);
            }

        __syncthreads();
        if (kt + 2 <= 7)
            stage_tile(Wbf + (size_t)(nb * 8 + kt + 2) * 4096, &w_s[wbuf][0], t);
    }

    float* obuf = (float*)&a_s[0][0];
    #pragma unroll
    for (int mt = 0; mt < 2; ++mt)
        #pragma unroll
        for (int nt = 0; nt < 2; ++nt) {
            int ncol = wc * 32 + nt * 16 + lr;
            float bb = bias[nb * 64 + ncol];
            #pragma unroll
            for (int reg = 0; reg < 4; ++reg) {
                int mrow = wr * 32 + mt * 16 + lg * 4 + reg;
                obuf[mrow * 68 + ncol] = acc[mt][nt][reg] + bb;
            }
        }
    __syncthreads();

    #pragma unroll
    for (int i = 0; i < 4; ++i) {
        int row = i * 16 + (t >> 4);
        int col = (t & 15) * 4;
        float4 o4 = *(const float4*)&obuf[row * 68 + col];
        *(float4*)&C[(size_t)(bm * 64 + row) * 512 + nb * 64 + col] = o4;
    }
}

// ---------------------------------------------------------------------------
extern "C" void kernel_launch(void* const* d_in, const int* in_sizes, int n_in,
                              void* d_out, int out_size, void* d_ws, size_t ws_size,
                              hipStream_t stream) {
    const float* values = (const float*)d_in[0];
    const float* keys   = (const float*)d_in[1];
    const float* query  = (const float*)d_in[2];
    const int*   maskp  = (const int*)d_in[3];
    const float* fc_w   = (const float*)d_in[4];
    const float* fc_b   = (const float*)d_in[5];
    float* out = (float*)d_out;

    short* Abf = (short*)d_ws;                                    // 4 MB
    short* Wbf = Abf + (size_t)BATCH * SLEN * EMBED;              // 512 KB
    short* Kbf = Wbf + (size_t)EMBED * EMBED;                     // 4 MB
    short* Vbf = Kbf + (size_t)BATCH * HEADS * NCHUNK * 4096;     // 4 MB
    float* vsum_part = (float*)(Vbf + (size_t)BATCH * HEADS * NCHUNK * 4096);
    float* gnum_part = vsum_part + (size_t)BATCH * 64 * EMBED;
    float* gden_part = gnum_part + (size_t)BATCH * HEADS * 64 * HDIM;
    float* nval_part = gden_part + (size_t)BATCH * HEADS * 64;

    prepass<<<dim3(1088), 256, 0, stream>>>(
        query, keys, values, maskp, fc_w, Kbf, Vbf, Wbf,
        gnum_part, gden_part, vsum_part, nval_part);
    windowed_attn_v12<<<dim3(256), 512, 0, stream>>>(
        query, Kbf, Vbf,
        gnum_part, gden_part, vsum_part, nval_part, Abf);
    fc_gemm_v6<<<dim3(64, 8), 256, 0, stream>>>(
        Abf, Wbf, fc_b, out);
}

// Round 17
// 30.882 us; speedup vs baseline: 1.0384x; 1.0384x over previous
//
#include <hip/hip_runtime.h>
#include <math.h>

#define EMBED 512
#define HEADS 8
#define HDIM 64
#define SLEN 2048
#define BATCH 2
#define HALFW 128
#define NCHUNK 32
#define INV_SCALE 0.044194173824159216f  // 1/sqrt(512)

typedef short bf16x8 __attribute__((ext_vector_type(8)));
typedef short s16x4  __attribute__((ext_vector_type(4)));
typedef float f32x4  __attribute__((ext_vector_type(4)));

#define MFMA16(a, b, c) __builtin_amdgcn_mfma_f32_16x16x32_bf16(a, b, c, 0, 0, 0)

__device__ __forceinline__ short f2bf(float x) {
    union { float f; unsigned u; } v; v.f = x;
    unsigned r = v.u + 0x7FFFu + ((v.u >> 16) & 1u);  // RNE
    return (short)(r >> 16);
}

// Blocked-frag layout for a 64x64 bf16 tile (global AND LDS), XOR-swizzled:
// 16B fragment (row, seg) at short index ((seg*64) + (row^seg)) * 8.
__device__ __forceinline__ int lidx(int row, int seg) {
    return (((seg << 6) + (row ^ seg)) << 3);
}

// async global->LDS, 16B per lane. dest: wave-uniform base, HW adds lane*16.
__device__ __forceinline__ void gll16(const short* g, short* l) {
    __builtin_amdgcn_global_load_lds(
        (const __attribute__((address_space(1))) unsigned int*)g,
        (__attribute__((address_space(3))) unsigned int*)l, 16, 0, 0);
}

// identity-copy two 8KB frag tiles (layout preserved: dest off == src off)
__device__ __forceinline__ void stage_chunk(const short* s0, const short* s1,
                                            short* d0, short* d1, int t) {
    int off = t * 8;              // shorts
    int wb  = (t >> 6) * 512;     // wave-uniform LDS base (shorts)
    gll16(s0 + off,        d0 + wb);
    gll16(s0 + 2048 + off, d0 + 2048 + wb);
    gll16(s1 + off,        d1 + wb);
    gll16(s1 + 2048 + off, d1 + 2048 + wb);
}

// stage one 8KB tile (2 gll16)
__device__ __forceinline__ void stage_tile(const short* s, short* d, int t) {
    int off = t * 8;
    int wb  = (t >> 6) * 512;
    gll16(s + off,        d + wb);
    gll16(s + 2048 + off, d + 2048 + wb);
}

// ---------------------------------------------------------------------------
// Kernel 1: prepass, HALF-CHUNK granularity (32 key-rows per block).
// grid 1088 1D, XCD-matched: XCD x owns hb8 in {2x,2x+1}; per hb8: 64
// half-chunks + 4 fc_w tiles. ~4.25 blocks/CU.
// Partials are per-half-chunk (64 slots), unique writer per slot.
// ---------------------------------------------------------------------------
__global__ __launch_bounds__(256) void prepass(
    const float* __restrict__ q, const float* __restrict__ k,
    const float* __restrict__ v, const int* __restrict__ mask,
    const float* __restrict__ fcw,
    short* __restrict__ Kbf, short* __restrict__ Vbf, short* __restrict__ Wbf,
    float* __restrict__ gnum_part, float* __restrict__ gden_part,
    float* __restrict__ vsum_part, float* __restrict__ nval_part) {
    int d = blockIdx.x;
    int x = d & 7, i = d >> 3;            // 136 works per XCD
    int hb8 = x * 2 + (i >= 68);          // 0..15 (= b*8 + h)
    int ii  = (i >= 68) ? (i - 68) : i;   // 0..67
    int h = hb8 & 7, b = hb8 >> 3;
    int t = threadIdx.x, w = t >> 6, l = t & 63;

    if (ii >= 64) {               // ---- fc_w tile -> Wbf frags ----
        int widx = hb8 * 4 + (ii - 64);   // 0..63
        int nb = widx >> 3, kt = widx & 7;
        size_t base = (size_t)(nb * 8 + kt) * 4096;
        #pragma unroll
        for (int p = 0; p < 4; ++p) {
            int idx = p * 256 + t, row = idx >> 4, kg = idx & 15;
            float4 f = *(const float4*)(fcw + (size_t)(nb * 64 + row) * EMBED + kt * 64 + kg * 4);
            s16x4 o;
            o[0] = f2bf(f.x); o[1] = f2bf(f.y); o[2] = f2bf(f.z); o[3] = f2bf(f.w);
            *(s16x4*)&Wbf[base + lidx(row, kg >> 1) + (kg & 1) * 4] = o;
        }
        return;
    }

    int ch  = ii;                 // half-chunk 0..63
    int c   = ch >> 1;            // 64-key chunk
    int rof = (ch & 1) * 32;      // row offset within chunk tile
    int j0  = ch * 32;            // global key start

    __shared__ float q0s[HDIM];
    __shared__ float wls[32];
    __shared__ int   m_s[32];
    __shared__ float vbuf[32][68];
    __shared__ float red[4][HDIM];
    __shared__ float redv[4][HDIM];

    if (t < 64) q0s[t] = q[(size_t)b * SLEN * EMBED + h * HDIM + t];
    else if (t < 96) m_s[t - 64] = mask[b * SLEN + j0 + (t - 64)];
    __syncthreads();

    size_t fragbase = ((size_t)(b * HEADS + h) * NCHUNK + c) * 4096;

    // ---- K half-chunk -> Kbf frags (masked rows zeroed) + row-0 dot ----
    #pragma unroll
    for (int p = 0; p < 2; ++p) {
        int idx = p * 256 + t, row = idx >> 4, kg = idx & 15;   // row 0..31
        float4 f = *(const float4*)(k + ((size_t)b * SLEN + j0 + row) * EMBED + h * HDIM + kg * 4);
        float dot = q0s[kg*4+0]*f.x + q0s[kg*4+1]*f.y + q0s[kg*4+2]*f.z + q0s[kg*4+3]*f.w;
        dot += __shfl_xor(dot, 1, 64);
        dot += __shfl_xor(dot, 2, 64);
        dot += __shfl_xor(dot, 4, 64);
        dot += __shfl_xor(dot, 8, 64);
        if ((t & 15) == 0) wls[row] = __expf(dot * INV_SCALE);
        if (!m_s[row]) f = make_float4(0.f, 0.f, 0.f, 0.f);
        s16x4 o;
        o[0] = f2bf(f.x); o[1] = f2bf(f.y); o[2] = f2bf(f.z); o[3] = f2bf(f.w);
        *(s16x4*)&Kbf[fragbase + lidx(rof + row, kg >> 1) + (kg & 1) * 4] = o;
    }

    // ---- V half-chunk -> LDS (fp32, padded) ----
    #pragma unroll
    for (int p = 0; p < 2; ++p) {
        int idx = p * 256 + t, row = idx >> 4, kg = idx & 15;
        float4 f = *(const float4*)(v + ((size_t)b * SLEN + j0 + row) * EMBED + h * HDIM + kg * 4);
        *(float4*)&vbuf[row][kg * 4] = f;
    }
    __syncthreads();

    // ---- row-0 PV + vsum partials: lane = d, wave w covers 8 j ----
    float num = 0.f, vs = 0.f;
    #pragma unroll
    for (int jj = 0; jj < 8; ++jj) {
        int jl = w * 8 + jj;
        float vv = vbuf[jl][l];
        num += wls[jl] * vv;
        if (m_s[jl]) vs += vv;
    }
    red[w][l] = num;
    redv[w][l] = vs;

    // ---- V -> Vbf transposed frags: wave w -> jseg rof/8 + w ----
    {
        int jseg = (ch & 1) * 4 + w;
        bf16x8 o;
        #pragma unroll
        for (int e = 0; e < 8; ++e) o[e] = f2bf(vbuf[w * 8 + e][l]);
        *(bf16x8*)&Vbf[fragbase + lidx(l, jseg)] = o;
    }
    __syncthreads();

    // ---- deterministic partial writes (unique writer per half-chunk slot) ----
    if (w == 0) {
        gnum_part[((size_t)(b * HEADS + h) * 64 + ch) * HDIM + l] =
            red[0][l] + red[1][l] + red[2][l] + red[3][l];
        vsum_part[((size_t)b * 64 + ch) * EMBED + h * HDIM + l] =
            redv[0][l] + redv[1][l] + redv[2][l] + redv[3][l];
    } else if (w == 1) {
        float s = (l < 32) ? wls[l] : 0.f;
        #pragma unroll
        for (int off = 32; off > 0; off >>= 1) s += __shfl_xor(s, off, 64);
        if (l == 0) gden_part[(size_t)(b * HEADS + h) * 64 + ch] = s;
    } else if (w == 2 && h == 0) {
        float cc = (l < 32 && m_s[l]) ? 1.f : 0.f;
        #pragma unroll
        for (int off = 32; off > 0; off >>= 1) cc += __shfl_xor(cc, off, 64);
        if (l == 0) nval_part[b * 64 + ch] = cc;
    }
}

// ---------------------------------------------------------------------------
// Kernel 2: windowed attention v9 — 4-buffer K/V, 3-ahead counted vmcnt,
// XCD-chunked work order matched to prepass placement. Partial reduction
// over 64 half-chunk slots (hidden under first stage).
// ---------------------------------------------------------------------------
__global__ __launch_bounds__(256) void windowed_attn_v9(
    const float* __restrict__ q, const float* __restrict__ k,
    const float* __restrict__ v, const int* __restrict__ mask,
    const short* __restrict__ Kbf, const short* __restrict__ Vbf,
    const float* __restrict__ gnum_part, const float* __restrict__ gden_part,
    const float* __restrict__ vsum_part, const float* __restrict__ nval_part,
    short* __restrict__ Abf) {
    int dsp = blockIdx.x;
    int wid = (dsp & 7) * 64 + (dsp >> 3);   // chunked: XCD x -> wids x*64..+63
    int tile = wid & 31, h = (wid >> 5) & 7, b = wid >> 8;
    int r0 = tile * 64;
    int t = threadIdx.x, w = t >> 6, l = t & 63;
    int lg = l >> 4, lr = l & 15;

    __shared__ __align__(16) short k_s[4][4096];
    __shared__ __align__(16) short v_s[4][4096];
    __shared__ __align__(16) short wT_s[4][16][72];
    __shared__ float rsum[64];
    __shared__ float vred[4][64];
    __shared__ float gred[4][64];
    __shared__ float nv_s, gd_s;

    size_t hb = (size_t)(b * HEADS + h) * NCHUNK;
    int bh = b * HEADS + h;

    int c0 = tile - 2; if (c0 < 0) c0 = 0;
    int c1 = tile + 2; if (c1 > NCHUNK - 1) c1 = NCHUNK - 1;

    stage_chunk(Kbf + (hb + c0) * 4096, Vbf + (hb + c0) * 4096,
                &k_s[0][0], &v_s[0][0], t);

    // ---- Q frags direct from global (fp32 -> bf16), consumed before loop ----
    const float* qrow = q + ((size_t)b * SLEN + r0 + w * 16 + lr) * EMBED + h * HDIM;
    float4 a0 = *(const float4*)(qrow + lg * 8);
    float4 a1 = *(const float4*)(qrow + lg * 8 + 4);
    float4 a2 = *(const float4*)(qrow + 32 + lg * 8);
    float4 a3 = *(const float4*)(qrow + 32 + lg * 8 + 4);
    bf16x8 qb0, qb1;
    qb0[0] = f2bf(a0.x); qb0[1] = f2bf(a0.y); qb0[2] = f2bf(a0.z); qb0[3] = f2bf(a0.w);
    qb0[4] = f2bf(a1.x); qb0[5] = f2bf(a1.y); qb0[6] = f2bf(a1.z); qb0[7] = f2bf(a1.w);
    qb1[0] = f2bf(a2.x); qb1[1] = f2bf(a2.y); qb1[2] = f2bf(a2.z); qb1[3] = f2bf(a2.w);
    qb1[4] = f2bf(a3.x); qb1[5] = f2bf(a3.y); qb1[6] = f2bf(a3.z); qb1[7] = f2bf(a3.w);

    // ---- reduce prepass half-chunk partials (hidden under stage(c0)) ----
    {
        float vp = 0.f;
        #pragma unroll
        for (int cc = 0; cc < 16; ++cc)
            vp += vsum_part[((size_t)b * 64 + w * 16 + cc) * EMBED + h * HDIM + l];
        vred[w][l] = vp;
        if (w == 0) {
            float nvv = nval_part[b * 64 + l];
            #pragma unroll
            for (int off = 32; off > 0; off >>= 1) nvv += __shfl_xor(nvv, off, 64);
            if (l == 0) nv_s = nvv;
        }
        if (tile == 0) {
            float gp = 0.f;
            #pragma unroll
            for (int cc = 0; cc < 16; ++cc)
                gp += gnum_part[((size_t)bh * 64 + w * 16 + cc) * HDIM + l];
            gred[w][l] = gp;
            if (w == 1) {
                float gdd = gden_part[(size_t)bh * 64 + l];
                #pragma unroll
                for (int off = 32; off > 0; off >>= 1) gdd += __shfl_xor(gdd, off, 64);
                if (l == 0) gd_s = gdd;
            }
        }
    }

    stage_chunk(Kbf + (hb + c0 + 1) * 4096, Vbf + (hb + c0 + 1) * 4096,
                &k_s[1][0], &v_s[1][0], t);
    stage_chunk(Kbf + (hb + c0 + 2) * 4096, Vbf + (hb + c0 + 2) * 4096,
                &k_s[2][0], &v_s[2][0], t);

    int center = r0 + w * 16 + lr - 1;
    int lo = center - HALFW, hi = center + HALFW;

    f32x4 pv[4];
    #pragma unroll
    for (int dt = 0; dt < 4; ++dt) pv[dt] = (f32x4){0.f, 0.f, 0.f, 0.f};
    float dacc = 0.f;

    int bi = 0;
    for (int c = c0; c <= c1; ++c) {
        // wait for stage(c); keep up to 2 newer stages (8 gll16) in flight
        int rem = c1 - c;
        if (rem >= 2)      { asm volatile("s_waitcnt vmcnt(8)" ::: "memory"); }
        else if (rem == 1) { asm volatile("s_waitcnt vmcnt(4)" ::: "memory"); }
        else               { asm volatile("s_waitcnt vmcnt(0)" ::: "memory"); }
        __syncthreads();

        int jc = c * 64;
        // ---- QK^T (S^T): A = K rows, B = Q ----
        #pragma unroll
        for (int jt = 0; jt < 4; ++jt) {
            bf16x8 ka0 = *(const bf16x8*)&k_s[bi][lidx(jt * 16 + lr, lg)];
            bf16x8 ka1 = *(const bf16x8*)&k_s[bi][lidx(jt * 16 + lr, 4 + lg)];
            f32x4 sT = (f32x4){0.f, 0.f, 0.f, 0.f};
            sT = MFMA16(ka0, qb0, sT);
            sT = MFMA16(ka1, qb1, sT);
            int jbase = jc + jt * 16 + lg * 4;
            s16x4 wq;
            #pragma unroll
            for (int r = 0; r < 4; ++r) {
                int j = jbase + r;
                float wgt = (j >= lo && j <= hi) ? (__expf(sT[r] * INV_SCALE) - 1.f) : 0.f;
                dacc += wgt;
                wq[r] = f2bf(wgt);
            }
            *(s16x4*)&wT_s[w][lr][jt * 16 + lg * 4] = wq;
        }

        // ---- PV: A = w^T strip (wave-private), B = V^T frags ----
        bf16x8 wa0 = *(const bf16x8*)&wT_s[w][lr][lg * 8];
        bf16x8 wa1 = *(const bf16x8*)&wT_s[w][lr][32 + lg * 8];
        #pragma unroll
        for (int dt = 0; dt < 4; ++dt) {
            bf16x8 va0 = *(const bf16x8*)&v_s[bi][lidx(dt * 16 + lr, lg)];
            bf16x8 va1 = *(const bf16x8*)&v_s[bi][lidx(dt * 16 + lr, 4 + lg)];
            pv[dt] = MFMA16(wa0, va0, pv[dt]);
            pv[dt] = MFMA16(wa1, va1, pv[dt]);
        }

        // stage chunk c+3 into buffer (bi+3)&3 = buffer of compute(c-1);
        // safe: all waves passed this iter's barrier after finishing c-1.
        if (c + 3 <= c1) {
            int bn = (bi + 3) & 3;
            stage_chunk(Kbf + (hb + c + 3) * 4096, Vbf + (hb + c + 3) * 4096,
                        &k_s[bn][0], &v_s[bn][0], t);
        }
        bi = (bi + 1) & 3;
    }

    // ---- single-key fixup: row r0, key jx = r0-129 ----
    float wfix = 0.f;
    int jx = r0 - 129;
    if (w == 0 && jx >= 0) {
        float qv = q[((size_t)b * SLEN + r0) * EMBED + h * HDIM + l];
        float kv = k[((size_t)b * SLEN + jx) * EMBED + h * HDIM + l];
        float dd = qv * kv;
        #pragma unroll
        for (int off = 32; off > 0; off >>= 1) dd += __shfl_xor(dd, off, 64);
        if (mask[b * SLEN + jx] != 0) wfix = __expf(dd * INV_SCALE) - 1.f;
        if (lg == 0) {
            #pragma unroll
            for (int dt = 0; dt < 4; ++dt)
                pv[dt][0] += wfix * v[((size_t)b * SLEN + jx) * EMBED + h * HDIM + dt * 16 + lr];
        }
    }

    // ---- row-sum reduce ----
    dacc += __shfl_xor(dacc, 16, 64);
    dacc += __shfl_xor(dacc, 32, 64);
    if (lg == 0) rsum[w * 16 + lr] = dacc + ((w == 0 && lr == 0) ? wfix : 0.f);
    __syncthreads();

    // ---- epilogue: write fc-A frag tile (row 0 from global-attn partials) ----
    float nv = nv_s;
    float invden[4];
    #pragma unroll
    for (int r = 0; r < 4; ++r)
        invden[r] = 1.f / (nv + rsum[w * 16 + lg * 4 + r]);

    short* Atile = Abf + ((size_t)(b * NCHUNK + tile) * 8 + h) * 4096;
    #pragma unroll
    for (int dt = 0; dt < 4; ++dt) {
        int d = dt * 16 + lr;
        float vs = vred[0][d] + vred[1][d] + vred[2][d] + vred[3][d];
        #pragma unroll
        for (int r = 0; r < 4; ++r) {
            int row_local = w * 16 + lg * 4 + r;
            float o;
            if (tile == 0 && row_local == 0)
                o = (gred[0][d] + gred[1][d] + gred[2][d] + gred[3][d]) / gd_s;
            else
                o = (pv[dt][r] + vs) * invden[r];
            Atile[lidx(row_local, d >> 3) + (d & 7)] = f2bf(o);
        }
    }
}

// ---------------------------------------------------------------------------
// Kernel 3: FC GEMM v5 — A-strip staged once, prologue A0,W0,W1,A1..A7 so
// iter 0 waits only 4 loads; counted vmcnt, no drains in the K loop.
// ---------------------------------------------------------------------------
__global__ __launch_bounds__(256) void fc_gemm_v5(
    const short* __restrict__ Abf, const short* __restrict__ Wbf,
    const float* __restrict__ bias, float* __restrict__ C) {
    int bm = blockIdx.x;          // 0..63
    int nb = blockIdx.y;          // 0..7
    int t = threadIdx.x, w = t >> 6, l = t & 63;
    int lg = l >> 4, lr = l & 15;
    int wr = w >> 1, wc = w & 1;

    __shared__ __align__(16) short a_s[8][4096];   // full A strip (64 KB)
    __shared__ __align__(16) short w_s[2][4096];   // W dbuf (16 KB)

    stage_tile(Abf + (size_t)(bm * 8 + 0) * 4096, &a_s[0][0], t);
    stage_tile(Wbf + (size_t)(nb * 8 + 0) * 4096, &w_s[0][0], t);
    stage_tile(Wbf + (size_t)(nb * 8 + 1) * 4096, &w_s[1][0], t);
    #pragma unroll
    for (int kt = 1; kt < 8; ++kt)
        stage_tile(Abf + (size_t)(bm * 8 + kt) * 4096, &a_s[kt][0], t);

    f32x4 acc[2][2];
    #pragma unroll
    for (int mt = 0; mt < 2; ++mt)
        #pragma unroll
        for (int nt = 0; nt < 2; ++nt) acc[mt][nt] = (f32x4){0.f, 0.f, 0.f, 0.f};

    for (int kt = 0; kt < 8; ++kt) {
        if (kt == 0)      { asm volatile("s_waitcnt vmcnt(16)" ::: "memory"); }
        else if (kt == 1) { asm volatile("s_waitcnt vmcnt(14)" ::: "memory"); }
        else if (kt < 7)  { asm volatile("s_waitcnt vmcnt(2)"  ::: "memory"); }
        else              { asm volatile("s_waitcnt vmcnt(0)"  ::: "memory"); }
        __syncthreads();

        bf16x8 af[2][2], bf_[2][2];
        #pragma unroll
        for (int mt = 0; mt < 2; ++mt) {
            af[mt][0] = *(const bf16x8*)&a_s[kt][lidx(wr * 32 + mt * 16 + lr, lg)];
            af[mt][1] = *(const bf16x8*)&a_s[kt][lidx(wr * 32 + mt * 16 + lr, 4 + lg)];
        }
        int wbuf = kt & 1;
        #pragma unroll
        for (int nt = 0; nt < 2; ++nt) {
            bf_[nt][0] = *(const bf16x8*)&w_s[wbuf][lidx(wc * 32 + nt * 16 + lr, lg)];
            bf_[nt][1] = *(const bf16x8*)&w_s[wbuf][lidx(wc * 32 + nt * 16 + lr, 4 + lg)];
        }
        #pragma unroll
        for (int mt = 0; mt < 2; ++mt)
            #pragma unroll
            for (int nt = 0; nt < 2; ++nt) {
                acc[mt][nt] = MFMA16(af[mt][0], bf_[nt][0], acc[mt][nt]);
                acc[mt][nt] = MFMA16(af[mt][1], bf_[nt][1], acc[mt][nt]);
            }

        __syncthreads();   // all waves done reading w_s[wbuf] before restage
        if (kt + 2 <= 7)
            stage_tile(Wbf + (size_t)(nb * 8 + kt + 2) * 4096, &w_s[wbuf][0], t);
    }

    #pragma unroll
    for (int mt = 0; mt < 2; ++mt)
        #pragma unroll
        for (int nt = 0; nt < 2; ++nt) {
            int n = nb * 64 + wc * 32 + nt * 16 + lr;
            float bb = bias[n];
            #pragma unroll
            for (int reg = 0; reg < 4; ++reg) {
                int m = bm * 64 + wr * 32 + mt * 16 + lg * 4 + reg;
                C[(size_t)m * 512 + n] = acc[mt][nt][reg] + bb;
            }
        }
}

// ---------------------------------------------------------------------------
extern "C" void kernel_launch(void* const* d_in, const int* in_sizes, int n_in,
                              void* d_out, int out_size, void* d_ws, size_t ws_size,
                              hipStream_t stream) {
    const float* values = (const float*)d_in[0];
    const float* keys   = (const float*)d_in[1];
    const float* query  = (const float*)d_in[2];
    const int*   maskp  = (const int*)d_in[3];
    const float* fc_w   = (const float*)d_in[4];
    const float* fc_b   = (const float*)d_in[5];
    float* out = (float*)d_out;

    short* Abf = (short*)d_ws;                                    // 4 MB
    short* Wbf = Abf + (size_t)BATCH * SLEN * EMBED;              // 512 KB
    short* Kbf = Wbf + (size_t)EMBED * EMBED;                     // 4 MB
    short* Vbf = Kbf + (size_t)BATCH * HEADS * NCHUNK * 4096;     // 4 MB
    float* vsum_part = (float*)(Vbf + (size_t)BATCH * HEADS * NCHUNK * 4096);
    float* gnum_part = vsum_part + (size_t)BATCH * 64 * EMBED;
    float* gden_part = gnum_part + (size_t)BATCH * HEADS * 64 * HDIM;
    float* nval_part = gden_part + (size_t)BATCH * HEADS * 64;

    prepass<<<dim3(1088), 256, 0, stream>>>(
        query, keys, values, maskp, fc_w, Kbf, Vbf, Wbf,
        gnum_part, gden_part, vsum_part, nval_part);
    windowed_attn_v9<<<dim3(512), 256, 0, stream>>>(
        query, keys, values, maskp, Kbf, Vbf,
        gnum_part, gden_part, vsum_part, nval_part, Abf);
    fc_gemm_v5<<<dim3(64, 8), 256, 0, stream>>>(
        Abf, Wbf, fc_b, out);
}